// Round 4
// baseline (637.365 us; speedup 1.0000x reference)
//
#include <hip/hip_runtime.h>

#define BTOT   131072
#define INDIM  128
#define OUTDIM 512
#define VBS    128
#define NCHUNK (BTOT / VBS)   // 1024
#define MAXIT  16
#define TTOL   1e-4f
#define EPS    1e-5f
#define TSTR   520            // tile row stride in halves (8 halves pad)

typedef _Float16 half8  __attribute__((ext_vector_type(8)));
typedef float    floatx4 __attribute__((ext_vector_type(4)));

// ---------------------------------------------------------------------------
// Kernel 0: convert W [512x128] fp32 -> fp16 into workspace (row-major [o][k])
// ---------------------------------------------------------------------------
__global__ void w_to_half_kernel(const float* __restrict__ W,
                                 _Float16* __restrict__ Wh) {
    int i = blockIdx.x * blockDim.x + threadIdx.x;   // float4 index, 0..16383
    const float4 v = ((const float4*)W)[i];
    union { _Float16 h[4]; uint2 u; } p;
    p.h[0] = (_Float16)v.x; p.h[1] = (_Float16)v.y;
    p.h[2] = (_Float16)v.z; p.h[3] = (_Float16)v.w;
    ((uint2*)Wh)[i] = p.u;
}

// ---------------------------------------------------------------------------
// Sparsemax over one row held by a 16-lane group, 32 values per lane.
// s,k reductions via 4-step shfl_xor (stays within the 16-lane group);
// tau via Michelot fixed point with group-uniform early exit.
// ---------------------------------------------------------------------------
__device__ __forceinline__ void sparsemax_row32(float (&x)[32], float* outp)
{
    // row max: in-lane tree (fmax is associative-safe) + 4 shfl steps
    float m[16];
    #pragma unroll
    for (int j = 0; j < 16; ++j) m[j] = fmaxf(x[2*j], x[2*j+1]);
    #pragma unroll
    for (int j = 0; j < 8; ++j)  m[j] = fmaxf(m[j], m[j+8]);
    #pragma unroll
    for (int j = 0; j < 4; ++j)  m[j] = fmaxf(m[j], m[j+4]);
    float mx = fmaxf(fmaxf(m[0], m[1]), fmaxf(m[2], m[3]));
    mx = fmaxf(mx, __shfl_xor(mx, 1));
    mx = fmaxf(mx, __shfl_xor(mx, 2));
    mx = fmaxf(mx, __shfl_xor(mx, 4));
    mx = fmaxf(mx, __shfl_xor(mx, 8));

    // Michelot: tau' = tau + (sum relu(x-tau) - 1)/count(x>tau); tau0 = max-1.
    // s,k are group-uniform after reduction -> uniform break per group.
    float tau = mx - 1.0f;
    #pragma unroll 1
    for (int it = 0; it < MAXIT; ++it) {
        float s0=0.f, s1=0.f, s2=0.f, s3=0.f;
        float k0=0.f, k1=0.f, k2=0.f, k3=0.f;
        #pragma unroll
        for (int j = 0; j < 32; j += 4) {
            float d0 = x[j+0] - tau, d1 = x[j+1] - tau;
            float d2 = x[j+2] - tau, d3 = x[j+3] - tau;
            s0 += fmaxf(d0, 0.f); k0 += (d0 > 0.f) ? 1.f : 0.f;
            s1 += fmaxf(d1, 0.f); k1 += (d1 > 0.f) ? 1.f : 0.f;
            s2 += fmaxf(d2, 0.f); k2 += (d2 > 0.f) ? 1.f : 0.f;
            s3 += fmaxf(d3, 0.f); k3 += (d3 > 0.f) ? 1.f : 0.f;
        }
        float s = (s0 + s1) + (s2 + s3);
        float k = (k0 + k1) + (k2 + k3);
        s += __shfl_xor(s, 1); k += __shfl_xor(k, 1);
        s += __shfl_xor(s, 2); k += __shfl_xor(k, 2);
        s += __shfl_xor(s, 4); k += __shfl_xor(k, 4);
        s += __shfl_xor(s, 8); k += __shfl_xor(k, 8);
        float ntau = tau + (s - 1.0f) / k;
        float delta = fabsf(ntau - tau);
        tau = ntau;
        if (delta <= TTOL) break;
    }

    #pragma unroll
    for (int j = 0; j < 4; ++j) {
        float4 o0, o1;
        o0.x = fmaxf(x[j*8+0] - tau, 0.f);
        o0.y = fmaxf(x[j*8+1] - tau, 0.f);
        o0.z = fmaxf(x[j*8+2] - tau, 0.f);
        o0.w = fmaxf(x[j*8+3] - tau, 0.f);
        o1.x = fmaxf(x[j*8+4] - tau, 0.f);
        o1.y = fmaxf(x[j*8+5] - tau, 0.f);
        o1.z = fmaxf(x[j*8+6] - tau, 0.f);
        o1.w = fmaxf(x[j*8+7] - tau, 0.f);
        *(float4*)(outp + j*128)     = o0;
        *(float4*)(outp + j*128 + 4) = o1;
    }
}

// ---------------------------------------------------------------------------
// K1: GEMM(fp16 MFMA) + GhostBN -> y (fp16, [BTOT][OUTDIM]) in workspace.
// One block per virtual batch of 128 rows, 1024 threads = 16 waves.
// Identical phases 0-3 of the fused kernel; phase 4 replaced by a coalesced
// LDS->global copy-out (half8 = 16B per lane -> 1 KB contiguous per wave-op).
// Rationale (round-3 counters): the fused kernel is structurally capped at
// 1 block/CU, 16 waves (64 acc AGPRs -> >=128 regs/wave), so its phases
// serialize with all pipes <27% busy. Splitting lets the sparsemax run at
// ~24 waves/CU in K2 while K1 stays GEMM-shaped. y (134 MB) mostly lives in
// the 256 MB L3 between K1 and K2.
// ---------------------------------------------------------------------------
__global__ void __launch_bounds__(1024)
gemm_bn_kernel(const float* __restrict__ feat,
               const _Float16* __restrict__ Wh,
               const float* __restrict__ gamma,
               const float* __restrict__ beta,
               _Float16* __restrict__ y)
{
    __shared__ __align__(16) _Float16 tile[VBS][TSTR];   // 133120 B
    __shared__ float lds_ab[2][OUTDIM];                  // 4096 B
    float* lds_sum = (float*)&tile[0][0];                // [8][512] overlay
    float* lds_sq  = lds_sum + 8 * OUTDIM;               // [8][512]

    const int tid   = threadIdx.x;
    const int w     = tid >> 6;      // wave 0..15
    const int lane  = tid & 63;
    const int i16   = lane & 15;
    const int quad  = lane >> 4;     // 0..3
    const int w8    = w & 7;         // row group 0..7
    const int ch    = w >> 3;        // col half 0..1
    const int chunk = blockIdx.x;
    const int row0  = chunk * VBS + w8 * 16;
    const int cb0   = ch * 256;

    // ---- A fragments ----
    half8 afrag[4];
    {
        const float* ap = feat + (size_t)(row0 + i16) * INDIM + quad * 8;
        #pragma unroll
        for (int kt = 0; kt < 4; ++kt) {
            float4 v0 = *(const float4*)(ap + kt * 32);
            float4 v1 = *(const float4*)(ap + kt * 32 + 4);
            half8 h;
            h[0]=(_Float16)v0.x; h[1]=(_Float16)v0.y; h[2]=(_Float16)v0.z; h[3]=(_Float16)v0.w;
            h[4]=(_Float16)v1.x; h[5]=(_Float16)v1.y; h[6]=(_Float16)v1.z; h[7]=(_Float16)v1.w;
            afrag[kt] = h;
        }
    }

    // ---- Phase 1: GEMM + per-column partial stats ----
    floatx4 acc[16];
    {
        const half8* wp0 = (const half8*)(Wh + (size_t)(cb0 + i16) * INDIM + quad * 8);
        #pragma unroll
        for (int t = 0; t < 16; ++t) {
            floatx4 c = {0.f, 0.f, 0.f, 0.f};
            #pragma unroll
            for (int kt = 0; kt < 4; ++kt) {
                half8 b = wp0[t * 256 + kt * 4];
                c = __builtin_amdgcn_mfma_f32_16x16x32_f16(afrag[kt], b, c, 0, 0, 0);
            }
            acc[t] = c;
            float s = c.x + c.y + c.z + c.w;
            float q = c.x*c.x + c.y*c.y + c.z*c.z + c.w*c.w;
            s += __shfl_xor(s, 16); q += __shfl_xor(q, 16);
            s += __shfl_xor(s, 32); q += __shfl_xor(q, 32);
            if (quad == 0) {
                lds_sum[w8 * OUTDIM + cb0 + t * 16 + i16] = s;
                lds_sq [w8 * OUTDIM + cb0 + t * 16 + i16] = q;
            }
        }
    }
    __syncthreads();

    // ---- Phase 2: reduce stats -> BN affine a,b ----
    if (tid < OUTDIM) {
        float s = 0.f, q = 0.f;
        #pragma unroll
        for (int j = 0; j < 8; ++j) {
            s += lds_sum[j * OUTDIM + tid];
            q += lds_sq [j * OUTDIM + tid];
        }
        float mean = s * (1.0f / VBS);
        float var  = q * (1.0f / VBS) - mean * mean;
        float rstd = 1.0f / sqrtf(var + EPS);
        float a = gamma[tid] * rstd;
        float b = beta[tid] - mean * a;
        lds_ab[0][tid] = a;
        lds_ab[1][tid] = b;
    }
    __syncthreads();

    // ---- Phase 3: normalize acc, pack fp16 into LDS tile ----
    {
        const int r0 = w8 * 16 + quad * 4;
        #pragma unroll
        for (int t = 0; t < 16; ++t) {
            const int c = cb0 + t * 16 + i16;
            const float a = lds_ab[0][c];
            const float b = lds_ab[1][c];
            floatx4 v = acc[t];
            tile[r0 + 0][c] = (_Float16)fmaf(v.x, a, b);
            tile[r0 + 1][c] = (_Float16)fmaf(v.y, a, b);
            tile[r0 + 2][c] = (_Float16)fmaf(v.z, a, b);
            tile[r0 + 3][c] = (_Float16)fmaf(v.w, a, b);
        }
    }
    __syncthreads();

    // ---- Phase 4: coalesced copy-out, wave w owns rows w*8..+7 ----
    // b128 LDS read (contiguous, conflict-free) -> 16B global store;
    // 64 lanes x 16B = one full 1 KB row per wave-instruction.
    #pragma unroll
    for (int rr = 0; rr < 8; ++rr) {
        const int r = w * 8 + rr;
        half8 h = *(const half8*)&tile[r][lane * 8];
        *(half8*)(y + (size_t)(chunk * VBS + r) * OUTDIM + lane * 8) = h;
    }
}

// ---------------------------------------------------------------------------
// K2: streaming sparsemax. Block = 256 threads (4 waves), 16 rows/block,
// grid 8192. Row-parallel: 16 lanes per row, 32 values/lane in registers.
// No LDS, small register footprint -> __launch_bounds__(256,6): ~85-reg cap,
// 24 waves/CU (vs 16 in the fused kernel) to hide the shfl/HBM latency
// chains that left VALUBusy at 24% in the fused version.
// Numerics identical to fused: x = fp32(priors) * fp32(fp16-normalized y).
// ---------------------------------------------------------------------------
__global__ void __launch_bounds__(256, 6)
sparsemax_kernel(const _Float16* __restrict__ y,
                 const float* __restrict__ priors,
                 float* __restrict__ out)
{
    const int lane = threadIdx.x & 63;
    const int wv   = threadIdx.x >> 6;    // 0..3
    const int i16  = lane & 15;
    const int g    = lane >> 4;           // 0..3 row within wave
    const int row  = blockIdx.x * 16 + wv * 4 + g;
    const size_t gbase = (size_t)row * OUTDIM + i16 * 8;

    float x[32];
    #pragma unroll
    for (int j = 0; j < 4; ++j) {
        // 16 lanes x 16B = 256B contiguous per j (y); 2x256B fp32 (priors)
        half8  h  = *(const half8*)(y + gbase + j * 128);
        float4 p0 = *(const float4*)(priors + gbase + j * 128);
        float4 p1 = *(const float4*)(priors + gbase + j * 128 + 4);
        x[j*8+0] = (float)h[0] * p0.x; x[j*8+1] = (float)h[1] * p0.y;
        x[j*8+2] = (float)h[2] * p0.z; x[j*8+3] = (float)h[3] * p0.w;
        x[j*8+4] = (float)h[4] * p1.x; x[j*8+5] = (float)h[5] * p1.y;
        x[j*8+6] = (float)h[6] * p1.z; x[j*8+7] = (float)h[7] * p1.w;
    }
    sparsemax_row32(x, out + gbase);
}

// ---------------------------------------------------------------------------
// Fallback: the proven round-1 fused kernel (263 us), used only if the
// workspace cannot hold the fp16 intermediate y.
// ---------------------------------------------------------------------------
__global__ void __launch_bounds__(1024)
fused_all(const float* __restrict__ priors,
          const float* __restrict__ feat,
          const _Float16* __restrict__ Wh,
          const float* __restrict__ gamma,
          const float* __restrict__ beta,
          float* __restrict__ out)
{
    __shared__ __align__(16) _Float16 tile[VBS][TSTR];
    __shared__ float lds_ab[2][OUTDIM];
    float* lds_sum = (float*)&tile[0][0];
    float* lds_sq  = lds_sum + 8 * OUTDIM;

    const int tid   = threadIdx.x;
    const int w     = tid >> 6;
    const int lane  = tid & 63;
    const int i16   = lane & 15;
    const int quad  = lane >> 4;
    const int w8    = w & 7;
    const int ch    = w >> 3;
    const int chunk = blockIdx.x;
    const int row0  = chunk * VBS + w8 * 16;
    const int cb0   = ch * 256;

    half8 afrag[4];
    {
        const float* ap = feat + (size_t)(row0 + i16) * INDIM + quad * 8;
        #pragma unroll
        for (int kt = 0; kt < 4; ++kt) {
            float4 v0 = *(const float4*)(ap + kt * 32);
            float4 v1 = *(const float4*)(ap + kt * 32 + 4);
            half8 h;
            h[0]=(_Float16)v0.x; h[1]=(_Float16)v0.y; h[2]=(_Float16)v0.z; h[3]=(_Float16)v0.w;
            h[4]=(_Float16)v1.x; h[5]=(_Float16)v1.y; h[6]=(_Float16)v1.z; h[7]=(_Float16)v1.w;
            afrag[kt] = h;
        }
    }

    floatx4 acc[16];
    {
        const half8* wp0 = (const half8*)(Wh + (size_t)(cb0 + i16) * INDIM + quad * 8);
        #pragma unroll
        for (int t = 0; t < 16; ++t) {
            floatx4 c = {0.f, 0.f, 0.f, 0.f};
            #pragma unroll
            for (int kt = 0; kt < 4; ++kt) {
                half8 b = wp0[t * 256 + kt * 4];
                c = __builtin_amdgcn_mfma_f32_16x16x32_f16(afrag[kt], b, c, 0, 0, 0);
            }
            acc[t] = c;
            float s = c.x + c.y + c.z + c.w;
            float q = c.x*c.x + c.y*c.y + c.z*c.z + c.w*c.w;
            s += __shfl_xor(s, 16); q += __shfl_xor(q, 16);
            s += __shfl_xor(s, 32); q += __shfl_xor(q, 32);
            if (quad == 0) {
                lds_sum[w8 * OUTDIM + cb0 + t * 16 + i16] = s;
                lds_sq [w8 * OUTDIM + cb0 + t * 16 + i16] = q;
            }
        }
    }
    __syncthreads();

    if (tid < OUTDIM) {
        float s = 0.f, q = 0.f;
        #pragma unroll
        for (int j = 0; j < 8; ++j) {
            s += lds_sum[j * OUTDIM + tid];
            q += lds_sq [j * OUTDIM + tid];
        }
        float mean = s * (1.0f / VBS);
        float var  = q * (1.0f / VBS) - mean * mean;
        float rstd = 1.0f / sqrtf(var + EPS);
        float a = gamma[tid] * rstd;
        float b = beta[tid] - mean * a;
        lds_ab[0][tid] = a;
        lds_ab[1][tid] = b;
    }
    __syncthreads();

    {
        const int r0 = w8 * 16 + quad * 4;
        #pragma unroll
        for (int t = 0; t < 16; ++t) {
            const int c = cb0 + t * 16 + i16;
            const float a = lds_ab[0][c];
            const float b = lds_ab[1][c];
            floatx4 v = acc[t];
            tile[r0 + 0][c] = (_Float16)fmaf(v.x, a, b);
            tile[r0 + 1][c] = (_Float16)fmaf(v.y, a, b);
            tile[r0 + 2][c] = (_Float16)fmaf(v.z, a, b);
            tile[r0 + 3][c] = (_Float16)fmaf(v.w, a, b);
        }
    }

    const size_t gbaseA = (size_t)(chunk * VBS + w * 8 + quad) * OUTDIM + i16 * 8;
    float xa[32];
    #pragma unroll
    for (int j = 0; j < 4; ++j) {
        float4 p0 = *(const float4*)(priors + gbaseA + j * 128);
        float4 p1 = *(const float4*)(priors + gbaseA + j * 128 + 4);
        xa[j*8+0] = p0.x; xa[j*8+1] = p0.y; xa[j*8+2] = p0.z; xa[j*8+3] = p0.w;
        xa[j*8+4] = p1.x; xa[j*8+5] = p1.y; xa[j*8+6] = p1.z; xa[j*8+7] = p1.w;
    }
    __syncthreads();

    {
        const int r = w * 8 + quad;
        #pragma unroll
        for (int j = 0; j < 4; ++j) {
            half8 h = *(const half8*)&tile[r][i16 * 8 + j * 128];
            xa[j*8+0] *= (float)h[0]; xa[j*8+1] *= (float)h[1];
            xa[j*8+2] *= (float)h[2]; xa[j*8+3] *= (float)h[3];
            xa[j*8+4] *= (float)h[4]; xa[j*8+5] *= (float)h[5];
            xa[j*8+6] *= (float)h[6]; xa[j*8+7] *= (float)h[7];
        }
        sparsemax_row32(xa, out + gbaseA);
    }

    const size_t gbaseB = gbaseA + (size_t)4 * OUTDIM;
    float xb[32];
    #pragma unroll
    for (int j = 0; j < 4; ++j) {
        float4 p0 = *(const float4*)(priors + gbaseB + j * 128);
        float4 p1 = *(const float4*)(priors + gbaseB + j * 128 + 4);
        xb[j*8+0] = p0.x; xb[j*8+1] = p0.y; xb[j*8+2] = p0.z; xb[j*8+3] = p0.w;
        xb[j*8+4] = p1.x; xb[j*8+5] = p1.y; xb[j*8+6] = p1.z; xb[j*8+7] = p1.w;
    }
    {
        const int r = w * 8 + 4 + quad;
        #pragma unroll
        for (int j = 0; j < 4; ++j) {
            half8 h = *(const half8*)&tile[r][i16 * 8 + j * 128];
            xb[j*8+0] *= (float)h[0]; xb[j*8+1] *= (float)h[1];
            xb[j*8+2] *= (float)h[2]; xb[j*8+3] *= (float)h[3];
            xb[j*8+4] *= (float)h[4]; xb[j*8+5] *= (float)h[5];
            xb[j*8+6] *= (float)h[6]; xb[j*8+7] *= (float)h[7];
        }
        sparsemax_row32(xb, out + gbaseB);
    }
}

// ---------------------------------------------------------------------------
extern "C" void kernel_launch(void* const* d_in, const int* in_sizes, int n_in,
                              void* d_out, int out_size, void* d_ws, size_t ws_size,
                              hipStream_t stream) {
    const float* priors = (const float*)d_in[0];
    const float* feat   = (const float*)d_in[1];
    const float* W      = (const float*)d_in[2];
    const float* gamma  = (const float*)d_in[3];
    const float* beta   = (const float*)d_in[4];
    float* out = (float*)d_out;

    _Float16* Wh = (_Float16*)d_ws;                       // 128 KB
    const size_t wh_bytes = (size_t)OUTDIM * INDIM * 2;   // 131072
    const size_t y_bytes  = (size_t)BTOT * OUTDIM * 2;    // 134,217,728

    hipLaunchKernelGGL(w_to_half_kernel, dim3(64), dim3(256), 0, stream, W, Wh);

    if (ws_size >= wh_bytes + y_bytes) {
        _Float16* y = (_Float16*)((char*)d_ws + wh_bytes);
        hipLaunchKernelGGL(gemm_bn_kernel, dim3(NCHUNK), dim3(1024), 0, stream,
                           feat, Wh, gamma, beta, y);
        hipLaunchKernelGGL(sparsemax_kernel, dim3(BTOT / 16), dim3(256), 0, stream,
                           y, priors, out);
    } else {
        // workspace too small for the fp16 intermediate -> proven fused path
        hipLaunchKernelGGL(fused_all, dim3(NCHUNK), dim3(1024), 0, stream,
                           priors, feat, Wh, gamma, beta, out);
    }
}

// Round 5
// 633.114 us; speedup vs baseline: 1.0067x; 1.0067x over previous
//
#include <hip/hip_runtime.h>

#define BTOT   131072
#define INDIM  128
#define OUTDIM 512
#define VBS    128
#define NCHUNK (BTOT / VBS)   // 1024
#define MAXIT  16
#define TTOL   1e-4f
#define EPS    1e-5f
#define TSTR   520            // tile row stride in halves (fallback kernel)

typedef _Float16 half8  __attribute__((ext_vector_type(8)));
typedef float    floatx4 __attribute__((ext_vector_type(4)));

// ---------------------------------------------------------------------------
// Kernel 0: convert W [512x128] fp32 -> fp16 into workspace (row-major [o][k])
// ---------------------------------------------------------------------------
__global__ void w_to_half_kernel(const float* __restrict__ W,
                                 _Float16* __restrict__ Wh) {
    int i = blockIdx.x * blockDim.x + threadIdx.x;   // float4 index, 0..16383
    const float4 v = ((const float4*)W)[i];
    union { _Float16 h[4]; uint2 u; } p;
    p.h[0] = (_Float16)v.x; p.h[1] = (_Float16)v.y;
    p.h[2] = (_Float16)v.z; p.h[3] = (_Float16)v.w;
    ((uint2*)Wh)[i] = p.u;
}

// ---------------------------------------------------------------------------
// Sparsemax over one row held by a 16-lane group, 32 values per lane.
// ---------------------------------------------------------------------------
__device__ __forceinline__ void sparsemax_row32(float (&x)[32], float* outp)
{
    float m[16];
    #pragma unroll
    for (int j = 0; j < 16; ++j) m[j] = fmaxf(x[2*j], x[2*j+1]);
    #pragma unroll
    for (int j = 0; j < 8; ++j)  m[j] = fmaxf(m[j], m[j+8]);
    #pragma unroll
    for (int j = 0; j < 4; ++j)  m[j] = fmaxf(m[j], m[j+4]);
    float mx = fmaxf(fmaxf(m[0], m[1]), fmaxf(m[2], m[3]));
    mx = fmaxf(mx, __shfl_xor(mx, 1));
    mx = fmaxf(mx, __shfl_xor(mx, 2));
    mx = fmaxf(mx, __shfl_xor(mx, 4));
    mx = fmaxf(mx, __shfl_xor(mx, 8));

    // Michelot: tau' = tau + (sum relu(x-tau) - 1)/count(x>tau); tau0 = max-1.
    float tau = mx - 1.0f;
    #pragma unroll 1
    for (int it = 0; it < MAXIT; ++it) {
        float s0=0.f, s1=0.f, s2=0.f, s3=0.f;
        float k0=0.f, k1=0.f, k2=0.f, k3=0.f;
        #pragma unroll
        for (int j = 0; j < 32; j += 4) {
            float d0 = x[j+0] - tau, d1 = x[j+1] - tau;
            float d2 = x[j+2] - tau, d3 = x[j+3] - tau;
            s0 += fmaxf(d0, 0.f); k0 += (d0 > 0.f) ? 1.f : 0.f;
            s1 += fmaxf(d1, 0.f); k1 += (d1 > 0.f) ? 1.f : 0.f;
            s2 += fmaxf(d2, 0.f); k2 += (d2 > 0.f) ? 1.f : 0.f;
            s3 += fmaxf(d3, 0.f); k3 += (d3 > 0.f) ? 1.f : 0.f;
        }
        float s = (s0 + s1) + (s2 + s3);
        float k = (k0 + k1) + (k2 + k3);
        s += __shfl_xor(s, 1); k += __shfl_xor(k, 1);
        s += __shfl_xor(s, 2); k += __shfl_xor(k, 2);
        s += __shfl_xor(s, 4); k += __shfl_xor(k, 4);
        s += __shfl_xor(s, 8); k += __shfl_xor(k, 8);
        float ntau = tau + (s - 1.0f) / k;
        float delta = fabsf(ntau - tau);
        tau = ntau;
        if (delta <= TTOL) break;
    }

    #pragma unroll
    for (int j = 0; j < 4; ++j) {
        float4 o0, o1;
        o0.x = fmaxf(x[j*8+0] - tau, 0.f);
        o0.y = fmaxf(x[j*8+1] - tau, 0.f);
        o0.z = fmaxf(x[j*8+2] - tau, 0.f);
        o0.w = fmaxf(x[j*8+3] - tau, 0.f);
        o1.x = fmaxf(x[j*8+4] - tau, 0.f);
        o1.y = fmaxf(x[j*8+5] - tau, 0.f);
        o1.z = fmaxf(x[j*8+6] - tau, 0.f);
        o1.w = fmaxf(x[j*8+7] - tau, 0.f);
        *(float4*)(outp + j*128)     = o0;
        *(float4*)(outp + j*128 + 4) = o1;
    }
}

// ---------------------------------------------------------------------------
// K1 v2: GEMM -> RAW fp16 y (stored as-you-go) + BN stats -> ab[chunk].
// Round-4 counters showed K1 v1 at 177 us with all pipes <9% busy: the
// 130 KB re-layout tile forced 1 block/CU and serialized {feat burst ->
// L2 GEMM -> barriers -> normalize -> store burst}, leaving memory idle
// during compute and compute idle during bursts.
// This version:
//   - stores y_raw = fp16(acc) INSIDE the MFMA t-loop (4 global_store_short
//     per tile) so the 131 KB/block write stream overlaps the L2 b-frag
//     reads and MFMA issue continuously;
//   - acc is transient (4 regs, no 64-AGPR array) and the tile is gone:
//     LDS = 36 KB stats only, regs ~60 -> 2 blocks/CU become possible;
//   - normalization moves to K2 via ab[chunk][2][512] in workspace
//     (numerics: fp16 rounding now before the affine instead of after --
//     same relative error scale, absmax expected unchanged).
// ---------------------------------------------------------------------------
__global__ void __launch_bounds__(1024)
gemm_bn_kernel(const float* __restrict__ feat,
               const _Float16* __restrict__ Wh,
               const float* __restrict__ gamma,
               const float* __restrict__ beta,
               _Float16* __restrict__ y,
               float* __restrict__ ab)
{
    __shared__ float lds_sum[8][OUTDIM];   // 16 KB
    __shared__ float lds_sq [8][OUTDIM];   // 16 KB

    const int tid   = threadIdx.x;
    const int w     = tid >> 6;      // wave 0..15
    const int lane  = tid & 63;
    const int i16   = lane & 15;
    const int quad  = lane >> 4;     // 0..3
    const int w8    = w & 7;         // row group 0..7
    const int ch    = w >> 3;        // col half 0..1
    const int chunk = blockIdx.x;
    const int row0  = chunk * VBS + w8 * 16;
    const int cb0   = ch * 256;

    // ---- A fragments: A[m=lane&15][k=quad*8+j] per 32-wide k-tile ----
    half8 afrag[4];
    {
        const float* ap = feat + (size_t)(row0 + i16) * INDIM + quad * 8;
        #pragma unroll
        for (int kt = 0; kt < 4; ++kt) {
            float4 v0 = *(const float4*)(ap + kt * 32);
            float4 v1 = *(const float4*)(ap + kt * 32 + 4);
            half8 h;
            h[0]=(_Float16)v0.x; h[1]=(_Float16)v0.y; h[2]=(_Float16)v0.z; h[3]=(_Float16)v0.w;
            h[4]=(_Float16)v1.x; h[5]=(_Float16)v1.y; h[6]=(_Float16)v1.z; h[7]=(_Float16)v1.w;
            afrag[kt] = h;
        }
    }

    // ---- GEMM t-loop: MFMA -> stats -> immediate raw fp16 store ----
    // C-fragment layout (16x16x32): lane holds col cb0+t*16+i16,
    // rows row0 + quad*4 + {0,1,2,3} in c.x..c.w.
    const half8* wp0 = (const half8*)(Wh + (size_t)(cb0 + i16) * INDIM + quad * 8);
    _Float16* ybase = y + (size_t)(row0 + quad * 4) * OUTDIM + cb0 + i16;

    #pragma unroll
    for (int t = 0; t < 16; ++t) {
        floatx4 c = {0.f, 0.f, 0.f, 0.f};
        #pragma unroll
        for (int kt = 0; kt < 4; ++kt) {
            half8 b = wp0[t * 256 + kt * 4];
            c = __builtin_amdgcn_mfma_f32_16x16x32_f16(afrag[kt], b, c, 0, 0, 0);
        }
        // per-column stats over the wave's 16 rows
        float s = c.x + c.y + c.z + c.w;
        float q = c.x*c.x + c.y*c.y + c.z*c.z + c.w*c.w;
        s += __shfl_xor(s, 16); q += __shfl_xor(q, 16);
        s += __shfl_xor(s, 32); q += __shfl_xor(q, 32);
        if (quad == 0) {
            lds_sum[w8][cb0 + t * 16 + i16] = s;
            lds_sq [w8][cb0 + t * 16 + i16] = q;
        }
        // stream raw fp16 out now (overlaps next t's L2 loads + MFMA)
        _Float16* yp = ybase + t * 16;
        yp[0 * OUTDIM] = (_Float16)c.x;
        yp[1 * OUTDIM] = (_Float16)c.y;
        yp[2 * OUTDIM] = (_Float16)c.z;
        yp[3 * OUTDIM] = (_Float16)c.w;
    }
    __syncthreads();

    // ---- reduce stats across the 8 row-groups -> BN affine a,b -> ws ----
    if (tid < OUTDIM) {
        float s = 0.f, q = 0.f;
        #pragma unroll
        for (int j = 0; j < 8; ++j) {
            s += lds_sum[j][tid];
            q += lds_sq [j][tid];
        }
        float mean = s * (1.0f / VBS);
        float var  = q * (1.0f / VBS) - mean * mean;
        float rstd = 1.0f / sqrtf(var + EPS);
        float a = gamma[tid] * rstd;
        float b = beta[tid] - mean * a;
        float* abp = ab + (size_t)chunk * 2 * OUTDIM;
        abp[tid]          = a;
        abp[OUTDIM + tid] = b;
    }
}

// ---------------------------------------------------------------------------
// K2 v2: streaming normalize + priors + sparsemax. 256 threads, 16 rows per
// block, grid 8192. ab[chunk] staged in 4 KB LDS; x = (a*y_raw + b)*priors.
// Round-4 counters: the v1 of this kernel ran at ~4.9 TB/s (near-roofline);
// this version adds one fma + 4x b128 LDS reads per 8 elements.
// ---------------------------------------------------------------------------
__global__ void __launch_bounds__(256)
sparsemax_kernel(const _Float16* __restrict__ y,
                 const float* __restrict__ ab,
                 const float* __restrict__ priors,
                 float* __restrict__ out)
{
    __shared__ __align__(16) float lds_a[OUTDIM];
    __shared__ __align__(16) float lds_b[OUTDIM];

    const int chunk = blockIdx.x >> 3;    // 8 blocks (16 rows each) per chunk
    {
        const float* abp = ab + (size_t)chunk * 2 * OUTDIM;
        const int t = threadIdx.x;        // 0..255, 2 cols each
        float2 va = *(const float2*)(abp + 2 * t);
        float2 vb = *(const float2*)(abp + OUTDIM + 2 * t);
        lds_a[2*t] = va.x; lds_a[2*t+1] = va.y;
        lds_b[2*t] = vb.x; lds_b[2*t+1] = vb.y;
    }
    __syncthreads();

    const int lane = threadIdx.x & 63;
    const int wv   = threadIdx.x >> 6;    // 0..3
    const int i16  = lane & 15;
    const int g    = lane >> 4;           // 0..3 row within wave
    const int row  = blockIdx.x * 16 + wv * 4 + g;
    const size_t gbase = (size_t)row * OUTDIM + i16 * 8;
    const int c0 = i16 * 8;

    float x[32];
    #pragma unroll
    for (int j = 0; j < 4; ++j) {
        half8  h  = *(const half8*)(y + gbase + j * 128);
        float4 p0 = *(const float4*)(priors + gbase + j * 128);
        float4 p1 = *(const float4*)(priors + gbase + j * 128 + 4);
        float4 a0 = *(const float4*)&lds_a[c0 + j * 128];
        float4 a1 = *(const float4*)&lds_a[c0 + j * 128 + 4];
        float4 b0 = *(const float4*)&lds_b[c0 + j * 128];
        float4 b1 = *(const float4*)&lds_b[c0 + j * 128 + 4];
        x[j*8+0] = fmaf((float)h[0], a0.x, b0.x) * p0.x;
        x[j*8+1] = fmaf((float)h[1], a0.y, b0.y) * p0.y;
        x[j*8+2] = fmaf((float)h[2], a0.z, b0.z) * p0.z;
        x[j*8+3] = fmaf((float)h[3], a0.w, b0.w) * p0.w;
        x[j*8+4] = fmaf((float)h[4], a1.x, b1.x) * p1.x;
        x[j*8+5] = fmaf((float)h[5], a1.y, b1.y) * p1.y;
        x[j*8+6] = fmaf((float)h[6], a1.z, b1.z) * p1.z;
        x[j*8+7] = fmaf((float)h[7], a1.w, b1.w) * p1.w;
    }
    sparsemax_row32(x, out + gbase);
}

// ---------------------------------------------------------------------------
// Fallback: the proven round-1 fused kernel (263 us/dispatch), used only if
// the workspace cannot hold the fp16 intermediate + ab buffer.
// ---------------------------------------------------------------------------
__global__ void __launch_bounds__(1024)
fused_all(const float* __restrict__ priors,
          const float* __restrict__ feat,
          const _Float16* __restrict__ Wh,
          const float* __restrict__ gamma,
          const float* __restrict__ beta,
          float* __restrict__ out)
{
    __shared__ __align__(16) _Float16 tile[VBS][TSTR];
    __shared__ float lds_ab[2][OUTDIM];
    float* lds_sum = (float*)&tile[0][0];
    float* lds_sq  = lds_sum + 8 * OUTDIM;

    const int tid   = threadIdx.x;
    const int w     = tid >> 6;
    const int lane  = tid & 63;
    const int i16   = lane & 15;
    const int quad  = lane >> 4;
    const int w8    = w & 7;
    const int ch    = w >> 3;
    const int chunk = blockIdx.x;
    const int row0  = chunk * VBS + w8 * 16;
    const int cb0   = ch * 256;

    half8 afrag[4];
    {
        const float* ap = feat + (size_t)(row0 + i16) * INDIM + quad * 8;
        #pragma unroll
        for (int kt = 0; kt < 4; ++kt) {
            float4 v0 = *(const float4*)(ap + kt * 32);
            float4 v1 = *(const float4*)(ap + kt * 32 + 4);
            half8 h;
            h[0]=(_Float16)v0.x; h[1]=(_Float16)v0.y; h[2]=(_Float16)v0.z; h[3]=(_Float16)v0.w;
            h[4]=(_Float16)v1.x; h[5]=(_Float16)v1.y; h[6]=(_Float16)v1.z; h[7]=(_Float16)v1.w;
            afrag[kt] = h;
        }
    }

    floatx4 acc[16];
    {
        const half8* wp0 = (const half8*)(Wh + (size_t)(cb0 + i16) * INDIM + quad * 8);
        #pragma unroll
        for (int t = 0; t < 16; ++t) {
            floatx4 c = {0.f, 0.f, 0.f, 0.f};
            #pragma unroll
            for (int kt = 0; kt < 4; ++kt) {
                half8 b = wp0[t * 256 + kt * 4];
                c = __builtin_amdgcn_mfma_f32_16x16x32_f16(afrag[kt], b, c, 0, 0, 0);
            }
            acc[t] = c;
            float s = c.x + c.y + c.z + c.w;
            float q = c.x*c.x + c.y*c.y + c.z*c.z + c.w*c.w;
            s += __shfl_xor(s, 16); q += __shfl_xor(q, 16);
            s += __shfl_xor(s, 32); q += __shfl_xor(q, 32);
            if (quad == 0) {
                lds_sum[w8 * OUTDIM + cb0 + t * 16 + i16] = s;
                lds_sq [w8 * OUTDIM + cb0 + t * 16 + i16] = q;
            }
        }
    }
    __syncthreads();

    if (tid < OUTDIM) {
        float s = 0.f, q = 0.f;
        #pragma unroll
        for (int j = 0; j < 8; ++j) {
            s += lds_sum[j * OUTDIM + tid];
            q += lds_sq [j * OUTDIM + tid];
        }
        float mean = s * (1.0f / VBS);
        float var  = q * (1.0f / VBS) - mean * mean;
        float rstd = 1.0f / sqrtf(var + EPS);
        float a = gamma[tid] * rstd;
        float b = beta[tid] - mean * a;
        lds_ab[0][tid] = a;
        lds_ab[1][tid] = b;
    }
    __syncthreads();

    {
        const int r0 = w8 * 16 + quad * 4;
        #pragma unroll
        for (int t = 0; t < 16; ++t) {
            const int c = cb0 + t * 16 + i16;
            const float a = lds_ab[0][c];
            const float b = lds_ab[1][c];
            floatx4 v = acc[t];
            tile[r0 + 0][c] = (_Float16)fmaf(v.x, a, b);
            tile[r0 + 1][c] = (_Float16)fmaf(v.y, a, b);
            tile[r0 + 2][c] = (_Float16)fmaf(v.z, a, b);
            tile[r0 + 3][c] = (_Float16)fmaf(v.w, a, b);
        }
    }

    const size_t gbaseA = (size_t)(chunk * VBS + w * 8 + quad) * OUTDIM + i16 * 8;
    float xa[32];
    #pragma unroll
    for (int j = 0; j < 4; ++j) {
        float4 p0 = *(const float4*)(priors + gbaseA + j * 128);
        float4 p1 = *(const float4*)(priors + gbaseA + j * 128 + 4);
        xa[j*8+0] = p0.x; xa[j*8+1] = p0.y; xa[j*8+2] = p0.z; xa[j*8+3] = p0.w;
        xa[j*8+4] = p1.x; xa[j*8+5] = p1.y; xa[j*8+6] = p1.z; xa[j*8+7] = p1.w;
    }
    __syncthreads();

    {
        const int r = w * 8 + quad;
        #pragma unroll
        for (int j = 0; j < 4; ++j) {
            half8 h = *(const half8*)&tile[r][i16 * 8 + j * 128];
            xa[j*8+0] *= (float)h[0]; xa[j*8+1] *= (float)h[1];
            xa[j*8+2] *= (float)h[2]; xa[j*8+3] *= (float)h[3];
            xa[j*8+4] *= (float)h[4]; xa[j*8+5] *= (float)h[5];
            xa[j*8+6] *= (float)h[6]; xa[j*8+7] *= (float)h[7];
        }
        sparsemax_row32(xa, out + gbaseA);
    }

    const size_t gbaseB = gbaseA + (size_t)4 * OUTDIM;
    float xb[32];
    #pragma unroll
    for (int j = 0; j < 4; ++j) {
        float4 p0 = *(const float4*)(priors + gbaseB + j * 128);
        float4 p1 = *(const float4*)(priors + gbaseB + j * 128 + 4);
        xb[j*8+0] = p0.x; xb[j*8+1] = p0.y; xb[j*8+2] = p0.z; xb[j*8+3] = p0.w;
        xb[j*8+4] = p1.x; xb[j*8+5] = p1.y; xb[j*8+6] = p1.z; xb[j*8+7] = p1.w;
    }
    {
        const int r = w * 8 + 4 + quad;
        #pragma unroll
        for (int j = 0; j < 4; ++j) {
            half8 h = *(const half8*)&tile[r][i16 * 8 + j * 128];
            xb[j*8+0] *= (float)h[0]; xb[j*8+1] *= (float)h[1];
            xb[j*8+2] *= (float)h[2]; xb[j*8+3] *= (float)h[3];
            xb[j*8+4] *= (float)h[4]; xb[j*8+5] *= (float)h[5];
            xb[j*8+6] *= (float)h[6]; xb[j*8+7] *= (float)h[7];
        }
        sparsemax_row32(xb, out + gbaseB);
    }
}

// ---------------------------------------------------------------------------
extern "C" void kernel_launch(void* const* d_in, const int* in_sizes, int n_in,
                              void* d_out, int out_size, void* d_ws, size_t ws_size,
                              hipStream_t stream) {
    const float* priors = (const float*)d_in[0];
    const float* feat   = (const float*)d_in[1];
    const float* W      = (const float*)d_in[2];
    const float* gamma  = (const float*)d_in[3];
    const float* beta   = (const float*)d_in[4];
    float* out = (float*)d_out;

    _Float16* Wh = (_Float16*)d_ws;                              // 128 KB
    const size_t wh_bytes = (size_t)OUTDIM * INDIM * 2;          // 131072
    const size_t ab_bytes = (size_t)NCHUNK * 2 * OUTDIM * 4;     // 4 MB
    const size_t y_bytes  = (size_t)BTOT * OUTDIM * 2;           // 134 MB

    hipLaunchKernelGGL(w_to_half_kernel, dim3(64), dim3(256), 0, stream, W, Wh);

    if (ws_size >= wh_bytes + ab_bytes + y_bytes) {
        float*    ab = (float*)((char*)d_ws + wh_bytes);
        _Float16* y  = (_Float16*)((char*)d_ws + wh_bytes + ab_bytes);
        hipLaunchKernelGGL(gemm_bn_kernel, dim3(NCHUNK), dim3(1024), 0, stream,
                           feat, Wh, gamma, beta, y, ab);
        hipLaunchKernelGGL(sparsemax_kernel, dim3(BTOT / 16), dim3(256), 0, stream,
                           y, ab, priors, out);
    } else {
        // workspace too small for the intermediates -> proven fused path
        hipLaunchKernelGGL(fused_all, dim3(NCHUNK), dim3(1024), 0, stream,
                           priors, feat, Wh, gamma, beta, out);
    }
}